// Round 4
// baseline (1127.001 us; speedup 1.0000x reference)
//
#include <hip/hip_runtime.h>
#include <hip/hip_bf16.h>

typedef __hip_bfloat16 bf16;
typedef __bf16 bf16x8 __attribute__((ext_vector_type(8)));
typedef float f32x4 __attribute__((ext_vector_type(4)));
typedef unsigned short u16;
typedef unsigned int u32;

#define SEQ 512
#define DMODEL 1024
#define FFDIM 4096
#define NHEAD 16
#define HDIM 64
#define NB 4
#define NLAYER 8

__device__ __forceinline__ u16 f2bu(float f) {
    union { bf16 h; u16 u; } c; c.h = __float2bfloat16(f); return c.u;
}

// async global->LDS, 16B per lane. LDS dest must be linear in lane order.
__device__ __forceinline__ void gload16(const bf16* g, bf16* l) {
    __builtin_amdgcn_global_load_lds(
        (const __attribute__((address_space(1))) unsigned int*)g,
        (__attribute__((address_space(3))) unsigned int*)l,
        16, 0, 0);
}

// ---------------------------------------------------------------------------
// NT GEMM core (m97 structure): C[m,n] = sum_k A[m,k]*B[n,k].
// Linear LDS, staged via global_load_lds dwordx4, 2-barrier K loop.
// ---------------------------------------------------------------------------
template<int BM, int BN, int BK, int WM, int WN>
__device__ __forceinline__ void gemm_core(
    const bf16* __restrict__ A, int lda,
    const bf16* __restrict__ B, int ldb,
    int K,
    f32x4 (&acc)[WM/16][WN/16],
    bf16* lA, bf16* lB)
{
    constexpr int NFM = WM / 16, NFN = WN / 16;
    constexpr int WC = BN / WN;
    const int tid  = threadIdx.x;
    const int lane = tid & 63, wave = tid >> 6;
    const int wr = wave / WC, wc = wave % WC;
    const int l15 = lane & 15, l4 = lane >> 4;

    constexpr int ITA = (BM * BK) / (256 * 8);
    constexpr int ITB = (BN * BK) / (256 * 8);

    for (int kt = 0; kt < K; kt += BK) {
        __syncthreads();
#pragma unroll
        for (int it = 0; it < ITA; ++it) {
            const int f = (it * 256 + tid) * 8;
            const int r = f / BK, c = f % BK;
            gload16(A + (long)r * lda + kt + c, lA + f);
        }
#pragma unroll
        for (int it = 0; it < ITB; ++it) {
            const int f = (it * 256 + tid) * 8;
            const int r = f / BK, c = f % BK;
            gload16(B + (long)r * ldb + kt + c, lB + f);
        }
        __syncthreads();
#pragma unroll
        for (int ks = 0; ks < BK / 32; ++ks) {
            bf16x8 af[NFM], bfr[NFN];
#pragma unroll
            for (int fm = 0; fm < NFM; ++fm)
                af[fm] = *(const bf16x8*)(lA + (wr * WM + fm * 16 + l15) * BK + ks * 32 + l4 * 8);
#pragma unroll
            for (int fn = 0; fn < NFN; ++fn)
                bfr[fn] = *(const bf16x8*)(lB + (wc * WN + fn * 16 + l15) * BK + ks * 32 + l4 * 8);
#pragma unroll
            for (int fm = 0; fm < NFM; ++fm)
#pragma unroll
                for (int fn = 0; fn < NFN; ++fn)
                    acc[fm][fn] = __builtin_amdgcn_mfma_f32_16x16x32_bf16(
                        af[fm], bfr[fn], acc[fm][fn], 0, 0, 0);
        }
    }
}

// ---------------------------------------------------------------------------
// LayerNorm: h (fp32, row of 1024) -> out bf16
// ---------------------------------------------------------------------------
__global__ __launch_bounds__(256) void k_ln(const float* __restrict__ h,
                                            const float* __restrict__ w,
                                            const float* __restrict__ bp,
                                            bf16* __restrict__ out)
{
    const int row = blockIdx.x;
    const int tid = threadIdx.x;
    const float4 x = ((const float4*)(h + (long)row * DMODEL))[tid];
    float s  = x.x + x.y + x.z + x.w;
    float s2 = x.x * x.x + x.y * x.y + x.z * x.z + x.w * x.w;
#pragma unroll
    for (int off = 32; off; off >>= 1) { s += __shfl_xor(s, off); s2 += __shfl_xor(s2, off); }
    __shared__ float rs[4], rs2[4];
    const int wave = tid >> 6;
    if ((tid & 63) == 0) { rs[wave] = s; rs2[wave] = s2; }
    __syncthreads();
    const float S1 = rs[0] + rs[1] + rs[2] + rs[3];
    const float S2 = rs2[0] + rs2[1] + rs2[2] + rs2[3];
    const float mean = S1 * (1.0f / DMODEL);
    const float var  = S2 * (1.0f / DMODEL) - mean * mean;
    const float rstd = rsqrtf(var + 1e-5f);
    const float4 wv = ((const float4*)w)[tid];
    const float4 bv = ((const float4*)bp)[tid];
    uint2 o;
    o.x = (u32)f2bu((x.x - mean) * rstd * wv.x + bv.x) |
          ((u32)f2bu((x.y - mean) * rstd * wv.y + bv.y) << 16);
    o.y = (u32)f2bu((x.z - mean) * rstd * wv.z + bv.z) |
          ((u32)f2bu((x.w - mean) * rstd * wv.w + bv.w) << 16);
    ((uint2*)(out + (long)row * DMODEL))[tid] = o;
}

// ---------------------------------------------------------------------------
// Convert per-layer q/k/v per-head weights fp32 -> packed bf16 [3][H][64][64]
// ---------------------------------------------------------------------------
__global__ __launch_bounds__(256) void k_cvt_qkvw(const float* __restrict__ qw,
                                                  const float* __restrict__ kw,
                                                  const float* __restrict__ vw,
                                                  bf16* __restrict__ wq)
{
    const int i = blockIdx.x * 256 + threadIdx.x;   // float4 index
    const int sel = i >> 14;
    const int off = i & 16383;
    const float* s = (sel == 0) ? qw : (sel == 1) ? kw : vw;
    const float4 v = ((const float4*)s)[off];
    uint2 o;
    o.x = (u32)f2bu(v.x) | ((u32)f2bu(v.y) << 16);
    o.y = (u32)f2bu(v.z) | ((u32)f2bu(v.w) << 16);
    ((uint2*)wq)[i] = o;
}

// ---------------------------------------------------------------------------
// Combined weight transpose for one layer: w1 [1024][4096] -> w1t [4096][1024]
// and w2 [4096][1024] -> w2t [1024][4096], fp32 -> bf16. grid 2048 blocks.
// ---------------------------------------------------------------------------
__global__ __launch_bounds__(256) void k_transw(const float* __restrict__ w1,
                                                const float* __restrict__ w2,
                                                bf16* __restrict__ w1t,
                                                bf16* __restrict__ w2t)
{
    __shared__ float t[64][65];
    int bid = blockIdx.x;
    const float* src; bf16* dst; int R, C, rb, cb;
    if (bid < 1024) {
        src = w1; dst = w1t; R = DMODEL; C = FFDIM;
        rb = (bid >> 6) << 6; cb = (bid & 63) << 6;
    } else {
        bid -= 1024;
        src = w2; dst = w2t; R = FFDIM; C = DMODEL;
        rb = (bid >> 4) << 6; cb = (bid & 15) << 6;
    }
    const int tid = threadIdx.x;
#pragma unroll
    for (int i = 0; i < 16; ++i) {
        int flat = i * 256 + tid;
        int r = flat >> 6, c = flat & 63;
        t[r][c] = src[(long)(rb + r) * C + cb + c];
    }
    __syncthreads();
#pragma unroll
    for (int i = 0; i < 16; ++i) {
        int flat = i * 256 + tid;
        int c = flat >> 6, r = flat & 63;
        dst[(long)(cb + c) * R + rb + r] = __float2bfloat16(t[r][c]);
    }
}

// ---------------------------------------------------------------------------
// Merged QKV: one block stages the shared y-slice A-tile once (in regs),
// then runs q/k/v weight tiles sequentially. grid (4, B*H).
// q scaled 1/8; v stored transposed vt[e][s].
// ---------------------------------------------------------------------------
__global__ __launch_bounds__(256) void k_qkv2(const bf16* __restrict__ y,
                                              const bf16* __restrict__ wq,
                                              const float* __restrict__ qb,
                                              const float* __restrict__ kb,
                                              const float* __restrict__ vb,
                                              bf16* __restrict__ qh,
                                              bf16* __restrict__ kh,
                                              bf16* __restrict__ vt)
{
    __shared__ __align__(16) char lmem[128 * 64 * 2 + 64 * 64 * 2];  // lA 16KB + lB 8KB
    bf16* lA = (bf16*)lmem;
    char* lBb = lmem + 128 * 64 * 2;

    const int tid = threadIdx.x;
    const int lane = tid & 63, wave = tid >> 6;
    const int l15 = lane & 15, l4 = lane >> 4;
    const int z = blockIdx.y;             // b*H + hd
    const int b = z >> 4, hd = z & 15;
    const bf16* A = y + (long)b * SEQ * DMODEL + hd * HDIM + (long)blockIdx.x * 128 * DMODEL;

    // stage A tile [128][64] linear
#pragma unroll
    for (int it = 0; it < 4; ++it) {
        const int f = (it * 256 + tid) * 8;
        const int r = f >> 6, c = f & 63;
        gload16(A + (long)r * DMODEL + c, lA + f);
    }
    __syncthreads();

    // A-fragments to registers: rows wave*32 + fm*16 + l15
    bf16x8 qa[2][2];
#pragma unroll
    for (int fm = 0; fm < 2; ++fm)
#pragma unroll
        for (int ks = 0; ks < 2; ++ks)
            qa[fm][ks] = *(const bf16x8*)(lA + (wave * 32 + fm * 16 + l15) * 64 + ks * 32 + l4 * 8);

    for (int t = 0; t < 3; ++t) {
        __syncthreads();   // lB reuse safe
        // stage B [64][64] with XOR swizzle (reg round-trip)
        const bf16* Bsrc = wq + (long)(t * NHEAD + hd) * HDIM * HDIM;
#pragma unroll
        for (int it = 0; it < 2; ++it) {
            const int f = (it * 256 + tid) * 8;
            const int r = f >> 6;
            const uint4 v = *(const uint4*)(Bsrc + f);
            int byte = (f << 1) ^ ((r & 7) << 4);
            *(uint4*)(lBb + byte) = v;
        }
        __syncthreads();

        bf16x8 bfr[4][2];
#pragma unroll
        for (int fn = 0; fn < 4; ++fn)
#pragma unroll
            for (int ks = 0; ks < 2; ++ks) {
                const int row = fn * 16 + l15;
                int byte = (row << 7) + ((ks * 32 + l4 * 8) << 1);
                byte ^= (row & 7) << 4;
                bfr[fn][ks] = *(const bf16x8*)(lBb + byte);
            }
        f32x4 acc[2][4] = {};
#pragma unroll
        for (int ks = 0; ks < 2; ++ks)
#pragma unroll
            for (int fm = 0; fm < 2; ++fm)
#pragma unroll
                for (int fn = 0; fn < 4; ++fn)
                    acc[fm][fn] = __builtin_amdgcn_mfma_f32_16x16x32_bf16(
                        qa[fm][ks], bfr[fn][ks], acc[fm][fn], 0, 0, 0);

        const float* bias = (t == 0) ? qb : (t == 1) ? kb : vb;
#pragma unroll
        for (int fm = 0; fm < 2; ++fm)
#pragma unroll
            for (int fn = 0; fn < 4; ++fn)
#pragma unroll
                for (int r = 0; r < 4; ++r) {
                    const int srow = blockIdx.x * 128 + wave * 32 + fm * 16 + l4 * 4 + r;
                    const int e = fn * 16 + l15;
                    float v = acc[fm][fn][r] + bias[hd * HDIM + e];
                    if (t == 0) {
                        qh[((long)z * SEQ + srow) * HDIM + e] = __float2bfloat16(v * 0.125f);
                    } else if (t == 1) {
                        kh[((long)z * SEQ + srow) * HDIM + e] = __float2bfloat16(v);
                    } else {
                        vt[((long)z * HDIM + e) * SEQ + srow] = __float2bfloat16(v);
                    }
                }
    }
}

// ---------------------------------------------------------------------------
// Flash attention: per block one (b,hd) head and 64 q-rows; loop over 8
// kv-tiles of 64 keys: S = qk^T (scale pre-folded), online softmax, O += P@V.
// grid (SEQ/64=8, B*H). h += O/l (residual).
// ---------------------------------------------------------------------------
__global__ __launch_bounds__(256) void k_flash(const bf16* __restrict__ qh,
                                               const bf16* __restrict__ kh,
                                               const bf16* __restrict__ vt,
                                               float* __restrict__ h)
{
    // lQ [64][64] 8KB (aliased per-wave as lP after q-frags move to regs)
    // lK [64][64] 8KB swizzled, lV [64][64] 8KB swizzled
    __shared__ __align__(16) char lmem[24576];
    bf16* lQ = (bf16*)lmem;
    char* lKb = lmem + 8192;
    char* lVb = lmem + 16384;

    const int tid = threadIdx.x;
    const int lane = tid & 63, wave = tid >> 6;
    const int l15 = lane & 15, l4 = lane >> 4;
    const int z = blockIdx.y;
    const int b = z >> 4, hd = z & 15;
    const int q0 = blockIdx.x * 64;

    // stage Q tile [64][64] linear
    const bf16* Qsrc = qh + ((long)z * SEQ + q0) * HDIM;
#pragma unroll
    for (int it = 0; it < 2; ++it) {
        const int f = (it * 256 + tid) * 8;
        gload16(Qsrc + f, lQ + f);
    }
    __syncthreads();

    // q A-frags: wave owns rows [wave*16, wave*16+16)
    bf16x8 qa[2];
#pragma unroll
    for (int ks = 0; ks < 2; ++ks)
        qa[ks] = *(const bf16x8*)(lQ + (wave * 16 + l15) * 64 + ks * 32 + l4 * 8);

    char* lPb = lmem + wave * 2048;   // wave-private, aliases its own lQ rows

    f32x4 O[4] = {};                  // [e-frag], rows = q
    float mrun[4], lrun[4];
#pragma unroll
    for (int r = 0; r < 4; ++r) { mrun[r] = -1e30f; lrun[r] = 0.0f; }

    for (int kv = 0; kv < SEQ / 64; ++kv) {
        __syncthreads();   // lK/lV reuse safe
        // stage K tile [key][64] swizzled
        const bf16* Ksrc = kh + ((long)z * SEQ + kv * 64) * HDIM;
#pragma unroll
        for (int it = 0; it < 2; ++it) {
            const int f = (it * 256 + tid) * 8;
            const int r = f >> 6;
            const uint4 v = *(const uint4*)(Ksrc + f);
            *(uint4*)(lKb + ((f << 1) ^ ((r & 7) << 4))) = v;
        }
        // stage V tile [e][key_local] swizzled (from vt[e][s])
        const bf16* Vsrc = vt + (long)z * HDIM * SEQ + kv * 64;
#pragma unroll
        for (int it = 0; it < 2; ++it) {
            const int f = (it * 256 + tid) * 8;
            const int r = f >> 6, c = f & 63;
            const uint4 v = *(const uint4*)(Vsrc + (long)r * SEQ + c);
            *(uint4*)(lVb + ((f << 1) ^ ((r & 7) << 4))) = v;
        }
        __syncthreads();

        // S = Q K^T : acc over ks
        f32x4 sa[4];
#pragma unroll
        for (int fn = 0; fn < 4; ++fn) sa[fn] = (f32x4){0.f, 0.f, 0.f, 0.f};
#pragma unroll
        for (int ks = 0; ks < 2; ++ks)
#pragma unroll
            for (int fn = 0; fn < 4; ++fn) {
                const int row = fn * 16 + l15;
                int byte = (row << 7) + ((ks * 32 + l4 * 8) << 1);
                byte ^= (row & 7) << 4;
                const bf16x8 kb_ = *(const bf16x8*)(lKb + byte);
                sa[fn] = __builtin_amdgcn_mfma_f32_16x16x32_bf16(qa[ks], kb_, sa[fn], 0, 0, 0);
            }

        // online softmax per q-row (row = l4*4 + r), cols across fn & l15
#pragma unroll
        for (int r = 0; r < 4; ++r) {
            float mx = fmaxf(fmaxf(sa[0][r], sa[1][r]), fmaxf(sa[2][r], sa[3][r]));
#pragma unroll
            for (int m_ = 1; m_ < 16; m_ <<= 1) mx = fmaxf(mx, __shfl_xor(mx, m_));
            const float nm = fmaxf(mrun[r], mx);
            const float al = __expf(mrun[r] - nm);
            mrun[r] = nm;
            float p0 = __expf(sa[0][r] - nm), p1 = __expf(sa[1][r] - nm);
            float p2 = __expf(sa[2][r] - nm), p3 = __expf(sa[3][r] - nm);
            float ps = p0 + p1 + p2 + p3;
#pragma unroll
            for (int m_ = 1; m_ < 16; m_ <<= 1) ps += __shfl_xor(ps, m_);
            lrun[r] = lrun[r] * al + ps;
#pragma unroll
            for (int fn = 0; fn < 4; ++fn) O[fn][r] *= al;
            // write P row to wave-private LDS (swizzled)
            const int row = l4 * 4 + r;
            const int rsw = (row & 7) << 4;
            const int rb = row << 7;
            *(u16*)(lPb + ((rb + ((0 * 16 + l15) << 1)) ^ rsw)) = f2bu(p0);
            *(u16*)(lPb + ((rb + ((1 * 16 + l15) << 1)) ^ rsw)) = f2bu(p1);
            *(u16*)(lPb + ((rb + ((2 * 16 + l15) << 1)) ^ rsw)) = f2bu(p2);
            *(u16*)(lPb + ((rb + ((3 * 16 + l15) << 1)) ^ rsw)) = f2bu(p3);
        }

        // PV: O += P @ V   (A = P rows q, k = key; B = V[e][key])
#pragma unroll
        for (int ks = 0; ks < 2; ++ks) {
            const int rowp = l15;
            int pbyte = (rowp << 7) + ((ks * 32 + l4 * 8) << 1);
            pbyte ^= (rowp & 7) << 4;
            const bf16x8 pa = *(const bf16x8*)(lPb + pbyte);
#pragma unroll
            for (int fn = 0; fn < 4; ++fn) {
                const int row = fn * 16 + l15;
                int byte = (row << 7) + ((ks * 32 + l4 * 8) << 1);
                byte ^= (row & 7) << 4;
                const bf16x8 vb_ = *(const bf16x8*)(lVb + byte);
                O[fn] = __builtin_amdgcn_mfma_f32_16x16x32_bf16(pa, vb_, O[fn], 0, 0, 0);
            }
        }
    }

    // epilogue: h += O / l
    float rinv[4];
#pragma unroll
    for (int r = 0; r < 4; ++r) rinv[r] = 1.0f / lrun[r];
#pragma unroll
    for (int fn = 0; fn < 4; ++fn)
#pragma unroll
        for (int r = 0; r < 4; ++r) {
            const int srow = q0 + wave * 16 + l4 * 4 + r;
            const int e = fn * 16 + l15;
            h[((long)b * SEQ + srow) * DMODEL + hd * HDIM + e] += O[fn][r] * rinv[r];
        }
}

// ---------------------------------------------------------------------------
// MLP GEMM1: ff1 = gelu(z @ w1t^T + b1), bf16 out. 64x128 tile, grid (32,32).
// ---------------------------------------------------------------------------
__global__ __launch_bounds__(256) void k_gemm1(const bf16* __restrict__ zb,
                                               const bf16* __restrict__ w1t,
                                               const float* __restrict__ b1,
                                               bf16* __restrict__ ff1)
{
    constexpr int BM = 64, BN = 128, BK = 64, WM = 32, WN = 64;
    __shared__ __align__(16) bf16 lA[BM * BK];
    __shared__ __align__(16) bf16 lB[BN * BK];
    const bf16* A = zb + (long)blockIdx.x * BM * DMODEL;
    const bf16* B = w1t + (long)blockIdx.y * BN * DMODEL;
    f32x4 acc[2][4] = {};
    gemm_core<BM, BN, BK, WM, WN>(A, DMODEL, B, DMODEL, DMODEL, acc, lA, lB);

    const int lane = threadIdx.x & 63, wave = threadIdx.x >> 6;
    const int wr = wave >> 1, wc = wave & 1, l15 = lane & 15, l4 = lane >> 4;
#pragma unroll
    for (int fm = 0; fm < 2; ++fm)
#pragma unroll
        for (int fn = 0; fn < 4; ++fn)
#pragma unroll
            for (int r = 0; r < 4; ++r) {
                const int row = blockIdx.x * BM + wr * WM + fm * 16 + l4 * 4 + r;
                const int col = blockIdx.y * BN + wc * WN + fn * 16 + l15;
                const float x = acc[fm][fn][r] + b1[col];
                const float g = 0.5f * x * (1.0f + erff(x * 0.70710678118f));
                ff1[(long)row * FFDIM + col] = __float2bfloat16(g);
            }
}

// ---------------------------------------------------------------------------
// MLP GEMM2 split-K: part[sk] = ff1[:,sk] @ w2t[:,sk]^T. 64x128, grid (32,8,4)
// ---------------------------------------------------------------------------
__global__ __launch_bounds__(256) void k_gemm2(const bf16* __restrict__ ff1,
                                               const bf16* __restrict__ w2t,
                                               float* __restrict__ part)
{
    constexpr int BM = 64, BN = 128, BK = 64, WM = 32, WN = 64;
    constexpr int KSPLIT = FFDIM / 4;   // 1024
    __shared__ __align__(16) bf16 lA[BM * BK];
    __shared__ __align__(16) bf16 lB[BN * BK];
    const int sk = blockIdx.z;
    const bf16* A = ff1 + (long)blockIdx.x * BM * FFDIM + (long)sk * KSPLIT;
    const bf16* B = w2t + (long)blockIdx.y * BN * FFDIM + (long)sk * KSPLIT;
    f32x4 acc[2][4] = {};
    gemm_core<BM, BN, BK, WM, WN>(A, FFDIM, B, FFDIM, KSPLIT, acc, lA, lB);

    float* out = part + (long)sk * (NB * SEQ) * DMODEL;
    const int lane = threadIdx.x & 63, wave = threadIdx.x >> 6;
    const int wr = wave >> 1, wc = wave & 1, l15 = lane & 15, l4 = lane >> 4;
#pragma unroll
    for (int fm = 0; fm < 2; ++fm)
#pragma unroll
        for (int fn = 0; fn < 4; ++fn)
#pragma unroll
            for (int r = 0; r < 4; ++r) {
                const int row = blockIdx.x * BM + wr * WM + fm * 16 + l4 * 4 + r;
                const int col = blockIdx.y * BN + wc * WN + fn * 16 + l15;
                out[(long)row * DMODEL + col] = acc[fm][fn][r];
            }
}

// ---------------------------------------------------------------------------
// Fused: h += sum_k part[k] + b2 (residual), then optionally y = LN(h) with
// next layer's ln1 params. One block per row (2048 blocks).
// ---------------------------------------------------------------------------
__global__ __launch_bounds__(256) void k_red2ln(const float* __restrict__ part,
                                                const float* __restrict__ b2,
                                                float* __restrict__ h,
                                                const float* __restrict__ lnw,
                                                const float* __restrict__ lnb,
                                                bf16* __restrict__ y,
                                                int do_ln)
{
    constexpr long NELT = (long)NB * SEQ * DMODEL / 4;   // float4 count
    const long row = blockIdx.x;
    const int tid = threadIdx.x;
    const long i = row * (DMODEL / 4) + tid;
    float4 s = ((const float4*)part)[i];
    const float4 s1 = ((const float4*)part)[i + NELT];
    const float4 s2 = ((const float4*)part)[i + 2 * NELT];
    const float4 s3 = ((const float4*)part)[i + 3 * NELT];
    const float4 bv = ((const float4*)b2)[tid];
    float4 hv = ((float4*)h)[i];
    hv.x += s.x + s1.x + s2.x + s3.x + bv.x;
    hv.y += s.y + s1.y + s2.y + s3.y + bv.y;
    hv.z += s.z + s1.z + s2.z + s3.z + bv.z;
    hv.w += s.w + s1.w + s2.w + s3.w + bv.w;
    ((float4*)h)[i] = hv;

    if (!do_ln) return;
    float ss  = hv.x + hv.y + hv.z + hv.w;
    float ss2 = hv.x * hv.x + hv.y * hv.y + hv.z * hv.z + hv.w * hv.w;
#pragma unroll
    for (int off = 32; off; off >>= 1) { ss += __shfl_xor(ss, off); ss2 += __shfl_xor(ss2, off); }
    __shared__ float rs[4], rs2[4];
    const int wave = tid >> 6;
    if ((tid & 63) == 0) { rs[wave] = ss; rs2[wave] = ss2; }
    __syncthreads();
    const float S1 = rs[0] + rs[1] + rs[2] + rs[3];
    const float S2 = rs2[0] + rs2[1] + rs2[2] + rs2[3];
    const float mean = S1 * (1.0f / DMODEL);
    const float var  = S2 * (1.0f / DMODEL) - mean * mean;
    const float rstd = rsqrtf(var + 1e-5f);
    const float4 wv = ((const float4*)lnw)[tid];
    const float4 lb = ((const float4*)lnb)[tid];
    uint2 o;
    o.x = (u32)f2bu((hv.x - mean) * rstd * wv.x + lb.x) |
          ((u32)f2bu((hv.y - mean) * rstd * wv.y + lb.y) << 16);
    o.y = (u32)f2bu((hv.z - mean) * rstd * wv.z + lb.z) |
          ((u32)f2bu((hv.w - mean) * rstd * wv.w + lb.w) << 16);
    ((uint2*)(y + row * DMODEL))[tid] = o;
}

// ---------------------------------------------------------------------------
extern "C" void kernel_launch(void* const* d_in, const int* in_sizes, int n_in,
                              void* d_out, int out_size, void* d_ws, size_t ws_size,
                              hipStream_t stream)
{
    const float* x    = (const float*)d_in[0];
    const float* ln1w = (const float*)d_in[1];
    const float* ln1b = (const float*)d_in[2];
    const float* qw   = (const float*)d_in[3];
    const float* qb   = (const float*)d_in[4];
    const float* kw   = (const float*)d_in[5];
    const float* kb   = (const float*)d_in[6];
    const float* vw   = (const float*)d_in[7];
    const float* vb   = (const float*)d_in[8];
    const float* ln2w = (const float*)d_in[9];
    const float* ln2b = (const float*)d_in[10];
    const float* w1   = (const float*)d_in[11];
    const float* b1   = (const float*)d_in[12];
    const float* w2   = (const float*)d_in[13];
    const float* b2   = (const float*)d_in[14];

    char* ws = (char*)d_ws;
    const size_t MB = 1024 * 1024;
    bf16* y    = (bf16*)(ws + 0 * MB);    // [2048,1024] bf16 : 4MB
    bf16* zb   = (bf16*)(ws + 4 * MB);    // [2048,1024] bf16 : 4MB
    bf16* qh   = (bf16*)(ws + 8 * MB);    // [B*H,512,64]     : 4MB
    bf16* kh   = (bf16*)(ws + 12 * MB);   // [B*H,512,64]     : 4MB
    bf16* vt   = (bf16*)(ws + 16 * MB);   // [B*H,64,512]     : 4MB
    bf16* ff1  = (bf16*)(ws + 20 * MB);   // [2048,4096]      : 16MB
    bf16* w1t  = (bf16*)(ws + 36 * MB);   // [4096,1024]      : 8MB
    bf16* w2t  = (bf16*)(ws + 44 * MB);   // [1024,4096]      : 8MB
    bf16* wqkv = (bf16*)(ws + 52 * MB);   // [3,16,64,64]     : 0.4MB
    float* part = (float*)(ws + 53 * MB); // [4,2048,1024] f32: 32MB

    float* h = (float*)d_out;
    hipMemcpyAsync(d_out, x, (size_t)NB * SEQ * DMODEL * sizeof(float),
                   hipMemcpyDeviceToDevice, stream);

    // initial LN1 for layer 0
    k_ln<<<NB * SEQ, 256, 0, stream>>>(h, ln1w, ln1b, y);

    for (int l = 0; l < NLAYER; ++l) {
        k_cvt_qkvw<<<192, 256, 0, stream>>>(qw + (long)l * 65536, kw + (long)l * 65536,
                                            vw + (long)l * 65536, wqkv);
        k_qkv2<<<dim3(4, NB * NHEAD), 256, 0, stream>>>(
            y, wqkv, qb + l * NHEAD * HDIM, kb + l * NHEAD * HDIM, vb + l * NHEAD * HDIM,
            qh, kh, vt);
        k_flash<<<dim3(SEQ / 64, NB * NHEAD), 256, 0, stream>>>(qh, kh, vt, h);
        k_ln<<<NB * SEQ, 256, 0, stream>>>(h, ln2w + l * DMODEL, ln2b + l * DMODEL, zb);
        k_transw<<<2048, 256, 0, stream>>>(w1 + (long)l * DMODEL * FFDIM,
                                           w2 + (long)l * DMODEL * FFDIM, w1t, w2t);
        k_gemm1<<<dim3(32, 32), 256, 0, stream>>>(zb, w1t, b1 + l * FFDIM, ff1);
        k_gemm2<<<dim3(32, 8, 4), 256, 0, stream>>>(ff1, w2t, part);
        const int last = (l == NLAYER - 1);
        k_red2ln<<<NB * SEQ, 256, 0, stream>>>(part, b2 + l * DMODEL, h,
                                               ln1w + (l + 1) * DMODEL * (1 - last),
                                               ln1b + (l + 1) * DMODEL * (1 - last),
                                               y, !last);
    }
}

// Round 5
// 1008.422 us; speedup vs baseline: 1.1176x; 1.1176x over previous
//
#include <hip/hip_runtime.h>
#include <hip/hip_bf16.h>

typedef __hip_bfloat16 bf16;
typedef __bf16 bf16x8 __attribute__((ext_vector_type(8)));
typedef float f32x4 __attribute__((ext_vector_type(4)));
typedef unsigned short u16;
typedef unsigned int u32;

#define SEQ 512
#define DMODEL 1024
#define FFDIM 4096
#define NHEAD 16
#define HDIM 64
#define NB 4
#define NLAYER 8

__device__ __forceinline__ u16 f2bu(float f) {
    union { bf16 h; u16 u; } c; c.h = __float2bfloat16(f); return c.u;
}

// async global->LDS, 16B per lane. LDS dest must be linear in lane order.
__device__ __forceinline__ void gload16(const bf16* g, bf16* l) {
    __builtin_amdgcn_global_load_lds(
        (const __attribute__((address_space(1))) unsigned int*)g,
        (__attribute__((address_space(3))) unsigned int*)l,
        16, 0, 0);
}

// ---------------------------------------------------------------------------
// NT GEMM core (m97 structure): C[m,n] = sum_k A[m,k]*B[n,k].
// Linear LDS, staged via global_load_lds dwordx4, 2-barrier K loop.
// ---------------------------------------------------------------------------
template<int BM, int BN, int BK, int WM, int WN>
__device__ __forceinline__ void gemm_core(
    const bf16* __restrict__ A, int lda,
    const bf16* __restrict__ B, int ldb,
    int K,
    f32x4 (&acc)[WM/16][WN/16],
    bf16* lA, bf16* lB)
{
    constexpr int NFM = WM / 16, NFN = WN / 16;
    constexpr int WC = BN / WN;
    const int tid  = threadIdx.x;
    const int lane = tid & 63, wave = tid >> 6;
    const int wr = wave / WC, wc = wave % WC;
    const int l15 = lane & 15, l4 = lane >> 4;

    constexpr int ITA = (BM * BK) / (256 * 8);
    constexpr int ITB = (BN * BK) / (256 * 8);

    for (int kt = 0; kt < K; kt += BK) {
        __syncthreads();
#pragma unroll
        for (int it = 0; it < ITA; ++it) {
            const int f = (it * 256 + tid) * 8;
            const int r = f / BK, c = f % BK;
            gload16(A + (long)r * lda + kt + c, lA + f);
        }
#pragma unroll
        for (int it = 0; it < ITB; ++it) {
            const int f = (it * 256 + tid) * 8;
            const int r = f / BK, c = f % BK;
            gload16(B + (long)r * ldb + kt + c, lB + f);
        }
        __syncthreads();
#pragma unroll
        for (int ks = 0; ks < BK / 32; ++ks) {
            bf16x8 af[NFM], bfr[NFN];
#pragma unroll
            for (int fm = 0; fm < NFM; ++fm)
                af[fm] = *(const bf16x8*)(lA + (wr * WM + fm * 16 + l15) * BK + ks * 32 + l4 * 8);
#pragma unroll
            for (int fn = 0; fn < NFN; ++fn)
                bfr[fn] = *(const bf16x8*)(lB + (wc * WN + fn * 16 + l15) * BK + ks * 32 + l4 * 8);
#pragma unroll
            for (int fm = 0; fm < NFM; ++fm)
#pragma unroll
                for (int fn = 0; fn < NFN; ++fn)
                    acc[fm][fn] = __builtin_amdgcn_mfma_f32_16x16x32_bf16(
                        af[fm], bfr[fn], acc[fm][fn], 0, 0, 0);
        }
    }
}

// ---------------------------------------------------------------------------
// LayerNorm: h (fp32, row of 1024) -> out bf16
// ---------------------------------------------------------------------------
__global__ __launch_bounds__(256) void k_ln(const float* __restrict__ h,
                                            const float* __restrict__ w,
                                            const float* __restrict__ bp,
                                            bf16* __restrict__ out)
{
    const int row = blockIdx.x;
    const int tid = threadIdx.x;
    const float4 x = ((const float4*)(h + (long)row * DMODEL))[tid];
    float s  = x.x + x.y + x.z + x.w;
    float s2 = x.x * x.x + x.y * x.y + x.z * x.z + x.w * x.w;
#pragma unroll
    for (int off = 32; off; off >>= 1) { s += __shfl_xor(s, off); s2 += __shfl_xor(s2, off); }
    __shared__ float rs[4], rs2[4];
    const int wave = tid >> 6;
    if ((tid & 63) == 0) { rs[wave] = s; rs2[wave] = s2; }
    __syncthreads();
    const float S1 = rs[0] + rs[1] + rs[2] + rs[3];
    const float S2 = rs2[0] + rs2[1] + rs2[2] + rs2[3];
    const float mean = S1 * (1.0f / DMODEL);
    const float var  = S2 * (1.0f / DMODEL) - mean * mean;
    const float rstd = rsqrtf(var + 1e-5f);
    const float4 wv = ((const float4*)w)[tid];
    const float4 bv = ((const float4*)bp)[tid];
    uint2 o;
    o.x = (u32)f2bu((x.x - mean) * rstd * wv.x + bv.x) |
          ((u32)f2bu((x.y - mean) * rstd * wv.y + bv.y) << 16);
    o.y = (u32)f2bu((x.z - mean) * rstd * wv.z + bv.z) |
          ((u32)f2bu((x.w - mean) * rstd * wv.w + bv.w) << 16);
    ((uint2*)(out + (long)row * DMODEL))[tid] = o;
}

// ---------------------------------------------------------------------------
// Combined weight transpose for one layer: w1 [1024][4096] -> w1t [4096][1024]
// and w2 [4096][1024] -> w2t [1024][4096], fp32 -> bf16. grid 2048 blocks.
// ---------------------------------------------------------------------------
__global__ __launch_bounds__(256) void k_transw(const float* __restrict__ w1,
                                                const float* __restrict__ w2,
                                                bf16* __restrict__ w1t,
                                                bf16* __restrict__ w2t)
{
    __shared__ float t[64][65];
    int bid = blockIdx.x;
    const float* src; bf16* dst; int R, C, rb, cb;
    if (bid < 1024) {
        src = w1; dst = w1t; R = DMODEL; C = FFDIM;
        rb = (bid >> 6) << 6; cb = (bid & 63) << 6;
    } else {
        bid -= 1024;
        src = w2; dst = w2t; R = FFDIM; C = DMODEL;
        rb = (bid >> 4) << 6; cb = (bid & 15) << 6;
    }
    const int tid = threadIdx.x;
#pragma unroll
    for (int i = 0; i < 16; ++i) {
        int flat = i * 256 + tid;
        int r = flat >> 6, c = flat & 63;
        t[r][c] = src[(long)(rb + r) * C + cb + c];
    }
    __syncthreads();
#pragma unroll
    for (int i = 0; i < 16; ++i) {
        int flat = i * 256 + tid;
        int c = flat >> 6, r = flat & 63;
        dst[(long)(cb + c) * R + rb + r] = __float2bfloat16(t[r][c]);
    }
}

// ---------------------------------------------------------------------------
// Merged QKV with in-flight fp32->bf16 weight conversion.
// One block stages the shared y-slice A-tile once (regs), then q/k/v weight
// tiles sequentially. grid (4, B*H). q scaled 1/8; v stored transposed vt[e][s].
// ---------------------------------------------------------------------------
__global__ __launch_bounds__(256) void k_qkv2(const bf16* __restrict__ y,
                                              const float* __restrict__ qwl,
                                              const float* __restrict__ kwl,
                                              const float* __restrict__ vwl,
                                              const float* __restrict__ qb,
                                              const float* __restrict__ kb,
                                              const float* __restrict__ vb,
                                              bf16* __restrict__ qh,
                                              bf16* __restrict__ kh,
                                              bf16* __restrict__ vt)
{
    __shared__ __align__(16) char lmem[128 * 64 * 2 + 64 * 64 * 2];  // lA 16KB + lB 8KB
    bf16* lA = (bf16*)lmem;
    char* lBb = lmem + 128 * 64 * 2;

    const int tid = threadIdx.x;
    const int lane = tid & 63, wave = tid >> 6;
    const int l15 = lane & 15, l4 = lane >> 4;
    const int z = blockIdx.y;             // b*H + hd
    const int b = z >> 4, hd = z & 15;
    const bf16* A = y + (long)b * SEQ * DMODEL + hd * HDIM + (long)blockIdx.x * 128 * DMODEL;

    // stage A tile [128][64] linear
#pragma unroll
    for (int it = 0; it < 4; ++it) {
        const int f = (it * 256 + tid) * 8;
        const int r = f >> 6, c = f & 63;
        gload16(A + (long)r * DMODEL + c, lA + f);
    }
    __syncthreads();

    // A-fragments to registers: rows wave*32 + fm*16 + l15
    bf16x8 qa[2][2];
#pragma unroll
    for (int fm = 0; fm < 2; ++fm)
#pragma unroll
        for (int ks = 0; ks < 2; ++ks)
            qa[fm][ks] = *(const bf16x8*)(lA + (wave * 32 + fm * 16 + l15) * 64 + ks * 32 + l4 * 8);

    for (int t = 0; t < 3; ++t) {
        __syncthreads();   // lB reuse safe
        // stage B [64][64] from fp32 weights, convert + XOR swizzle
        const float* Bsrc = ((t == 0) ? qwl : (t == 1) ? kwl : vwl) + (long)hd * HDIM * HDIM;
#pragma unroll
        for (int it = 0; it < 4; ++it) {
            const int f = (it * 256 + tid) * 4;         // float index
            const float4 v = *(const float4*)(Bsrc + f);
            uint2 o;
            o.x = (u32)f2bu(v.x) | ((u32)f2bu(v.y) << 16);
            o.y = (u32)f2bu(v.z) | ((u32)f2bu(v.w) << 16);
            const int row = f >> 6;
            const int byte = (f << 1) ^ ((row & 7) << 4);
            *(uint2*)(lBb + byte) = o;
        }
        __syncthreads();

        bf16x8 bfr[4][2];
#pragma unroll
        for (int fn = 0; fn < 4; ++fn)
#pragma unroll
            for (int ks = 0; ks < 2; ++ks) {
                const int row = fn * 16 + l15;
                int byte = (row << 7) + ((ks * 32 + l4 * 8) << 1);
                byte ^= (row & 7) << 4;
                bfr[fn][ks] = *(const bf16x8*)(lBb + byte);
            }
        f32x4 acc[2][4] = {};
#pragma unroll
        for (int ks = 0; ks < 2; ++ks)
#pragma unroll
            for (int fm = 0; fm < 2; ++fm)
#pragma unroll
                for (int fn = 0; fn < 4; ++fn)
                    acc[fm][fn] = __builtin_amdgcn_mfma_f32_16x16x32_bf16(
                        qa[fm][ks], bfr[fn][ks], acc[fm][fn], 0, 0, 0);

        const float* bias = (t == 0) ? qb : (t == 1) ? kb : vb;
#pragma unroll
        for (int fm = 0; fm < 2; ++fm)
#pragma unroll
            for (int fn = 0; fn < 4; ++fn)
#pragma unroll
                for (int r = 0; r < 4; ++r) {
                    const int srow = blockIdx.x * 128 + wave * 32 + fm * 16 + l4 * 4 + r;
                    const int e = fn * 16 + l15;
                    float v = acc[fm][fn][r] + bias[hd * HDIM + e];
                    if (t == 0) {
                        qh[((long)z * SEQ + srow) * HDIM + e] = __float2bfloat16(v * 0.125f);
                    } else if (t == 1) {
                        kh[((long)z * SEQ + srow) * HDIM + e] = __float2bfloat16(v);
                    } else {
                        vt[((long)z * HDIM + e) * SEQ + srow] = __float2bfloat16(v);
                    }
                }
    }
}

// ---------------------------------------------------------------------------
// Flash attention: per block one (b,hd) head and 64 q-rows; loop over 8
// kv-tiles of 64 keys: S = qk^T (scale pre-folded), online softmax, O += P@V.
// grid (SEQ/64=8, B*H). h += O/l (residual).
// ---------------------------------------------------------------------------
__global__ __launch_bounds__(256) void k_flash(const bf16* __restrict__ qh,
                                               const bf16* __restrict__ kh,
                                               const bf16* __restrict__ vt,
                                               float* __restrict__ h)
{
    // lQ [64][64] 8KB (aliased per-wave as lP after q-frags move to regs)
    // lK [64][64] 8KB swizzled, lV [64][64] 8KB swizzled
    __shared__ __align__(16) char lmem[24576];
    bf16* lQ = (bf16*)lmem;
    char* lKb = lmem + 8192;
    char* lVb = lmem + 16384;

    const int tid = threadIdx.x;
    const int lane = tid & 63, wave = tid >> 6;
    const int l15 = lane & 15, l4 = lane >> 4;
    const int z = blockIdx.y;
    const int b = z >> 4, hd = z & 15;
    const int q0 = blockIdx.x * 64;

    // stage Q tile [64][64] linear
    const bf16* Qsrc = qh + ((long)z * SEQ + q0) * HDIM;
#pragma unroll
    for (int it = 0; it < 2; ++it) {
        const int f = (it * 256 + tid) * 8;
        gload16(Qsrc + f, lQ + f);
    }
    __syncthreads();

    // q A-frags: wave owns rows [wave*16, wave*16+16)
    bf16x8 qa[2];
#pragma unroll
    for (int ks = 0; ks < 2; ++ks)
        qa[ks] = *(const bf16x8*)(lQ + (wave * 16 + l15) * 64 + ks * 32 + l4 * 8);

    char* lPb = lmem + wave * 2048;   // wave-private, aliases its own lQ rows

    f32x4 O[4] = {};                  // [e-frag], rows = q
    float mrun[4], lrun[4];
#pragma unroll
    for (int r = 0; r < 4; ++r) { mrun[r] = -1e30f; lrun[r] = 0.0f; }

    for (int kv = 0; kv < SEQ / 64; ++kv) {
        __syncthreads();   // lK/lV reuse safe
        // stage K tile [key][64] swizzled
        const bf16* Ksrc = kh + ((long)z * SEQ + kv * 64) * HDIM;
#pragma unroll
        for (int it = 0; it < 2; ++it) {
            const int f = (it * 256 + tid) * 8;
            const int r = f >> 6;
            const uint4 v = *(const uint4*)(Ksrc + f);
            *(uint4*)(lKb + ((f << 1) ^ ((r & 7) << 4))) = v;
        }
        // stage V tile [e][key_local] swizzled (from vt[e][s])
        const bf16* Vsrc = vt + (long)z * HDIM * SEQ + kv * 64;
#pragma unroll
        for (int it = 0; it < 2; ++it) {
            const int f = (it * 256 + tid) * 8;
            const int r = f >> 6, c = f & 63;
            const uint4 v = *(const uint4*)(Vsrc + (long)r * SEQ + c);
            *(uint4*)(lVb + ((f << 1) ^ ((r & 7) << 4))) = v;
        }
        __syncthreads();

        // S = Q K^T : acc over ks
        f32x4 sa[4];
#pragma unroll
        for (int fn = 0; fn < 4; ++fn) sa[fn] = (f32x4){0.f, 0.f, 0.f, 0.f};
#pragma unroll
        for (int ks = 0; ks < 2; ++ks)
#pragma unroll
            for (int fn = 0; fn < 4; ++fn) {
                const int row = fn * 16 + l15;
                int byte = (row << 7) + ((ks * 32 + l4 * 8) << 1);
                byte ^= (row & 7) << 4;
                const bf16x8 kb_ = *(const bf16x8*)(lKb + byte);
                sa[fn] = __builtin_amdgcn_mfma_f32_16x16x32_bf16(qa[ks], kb_, sa[fn], 0, 0, 0);
            }

        // online softmax per q-row (row = l4*4 + r), cols across fn & l15
#pragma unroll
        for (int r = 0; r < 4; ++r) {
            float mx = fmaxf(fmaxf(sa[0][r], sa[1][r]), fmaxf(sa[2][r], sa[3][r]));
#pragma unroll
            for (int m_ = 1; m_ < 16; m_ <<= 1) mx = fmaxf(mx, __shfl_xor(mx, m_));
            const float nm = fmaxf(mrun[r], mx);
            const float al = __expf(mrun[r] - nm);
            mrun[r] = nm;
            float p0 = __expf(sa[0][r] - nm), p1 = __expf(sa[1][r] - nm);
            float p2 = __expf(sa[2][r] - nm), p3 = __expf(sa[3][r] - nm);
            float ps = p0 + p1 + p2 + p3;
#pragma unroll
            for (int m_ = 1; m_ < 16; m_ <<= 1) ps += __shfl_xor(ps, m_);
            lrun[r] = lrun[r] * al + ps;
#pragma unroll
            for (int fn = 0; fn < 4; ++fn) O[fn][r] *= al;
            // write P row to wave-private LDS (swizzled)
            const int row = l4 * 4 + r;
            const int rsw = (row & 7) << 4;
            const int rb = row << 7;
            *(u16*)(lPb + ((rb + ((0 * 16 + l15) << 1)) ^ rsw)) = f2bu(p0);
            *(u16*)(lPb + ((rb + ((1 * 16 + l15) << 1)) ^ rsw)) = f2bu(p1);
            *(u16*)(lPb + ((rb + ((2 * 16 + l15) << 1)) ^ rsw)) = f2bu(p2);
            *(u16*)(lPb + ((rb + ((3 * 16 + l15) << 1)) ^ rsw)) = f2bu(p3);
        }

        // PV: O += P @ V   (A = P rows q, k = key; B = V[e][key])
#pragma unroll
        for (int ks = 0; ks < 2; ++ks) {
            const int rowp = l15;
            int pbyte = (rowp << 7) + ((ks * 32 + l4 * 8) << 1);
            pbyte ^= (rowp & 7) << 4;
            const bf16x8 pa = *(const bf16x8*)(lPb + pbyte);
#pragma unroll
            for (int fn = 0; fn < 4; ++fn) {
                const int row = fn * 16 + l15;
                int byte = (row << 7) + ((ks * 32 + l4 * 8) << 1);
                byte ^= (row & 7) << 4;
                const bf16x8 vb_ = *(const bf16x8*)(lVb + byte);
                O[fn] = __builtin_amdgcn_mfma_f32_16x16x32_bf16(pa, vb_, O[fn], 0, 0, 0);
            }
        }
    }

    // epilogue: h += O / l
    float rinv[4];
#pragma unroll
    for (int r = 0; r < 4; ++r) rinv[r] = 1.0f / lrun[r];
#pragma unroll
    for (int fn = 0; fn < 4; ++fn)
#pragma unroll
        for (int r = 0; r < 4; ++r) {
            const int srow = q0 + wave * 16 + l4 * 4 + r;
            const int e = fn * 16 + l15;
            h[((long)b * SEQ + srow) * DMODEL + hd * HDIM + e] += O[fn][r] * rinv[r];
        }
}

// ---------------------------------------------------------------------------
// MLP GEMM1: ff1 = gelu(z @ w1t^T + b1), bf16 out. 128x128, grid (16,32).
// ---------------------------------------------------------------------------
__global__ __launch_bounds__(256) void k_gemm1(const bf16* __restrict__ zb,
                                               const bf16* __restrict__ w1t,
                                               const float* __restrict__ b1,
                                               bf16* __restrict__ ff1)
{
    constexpr int BM = 128, BN = 128, BK = 64, WM = 64, WN = 64;
    __shared__ __align__(16) bf16 lA[BM * BK];
    __shared__ __align__(16) bf16 lB[BN * BK];
    const bf16* A = zb + (long)blockIdx.x * BM * DMODEL;
    const bf16* B = w1t + (long)blockIdx.y * BN * DMODEL;
    f32x4 acc[4][4] = {};
    gemm_core<BM, BN, BK, WM, WN>(A, DMODEL, B, DMODEL, DMODEL, acc, lA, lB);

    const int lane = threadIdx.x & 63, wave = threadIdx.x >> 6;
    const int wr = wave >> 1, wc = wave & 1, l15 = lane & 15, l4 = lane >> 4;
#pragma unroll
    for (int fm = 0; fm < 4; ++fm)
#pragma unroll
        for (int fn = 0; fn < 4; ++fn)
#pragma unroll
            for (int r = 0; r < 4; ++r) {
                const int row = blockIdx.x * BM + wr * WM + fm * 16 + l4 * 4 + r;
                const int col = blockIdx.y * BN + wc * WN + fn * 16 + l15;
                const float x = acc[fm][fn][r] + b1[col];
                const float g = 0.5f * x * (1.0f + erff(x * 0.70710678118f));
                ff1[(long)row * FFDIM + col] = __float2bfloat16(g);
            }
}

// ---------------------------------------------------------------------------
// MLP GEMM2 split-K: part[sk] = ff1[:,sk] @ w2t[:,sk]^T. 128x128, grid (16,8,4)
// ---------------------------------------------------------------------------
__global__ __launch_bounds__(256) void k_gemm2(const bf16* __restrict__ ff1,
                                               const bf16* __restrict__ w2t,
                                               float* __restrict__ part)
{
    constexpr int BM = 128, BN = 128, BK = 64, WM = 64, WN = 64;
    constexpr int KSPLIT = FFDIM / 4;   // 1024
    __shared__ __align__(16) bf16 lA[BM * BK];
    __shared__ __align__(16) bf16 lB[BN * BK];
    const int sk = blockIdx.z;
    const bf16* A = ff1 + (long)blockIdx.x * BM * FFDIM + (long)sk * KSPLIT;
    const bf16* B = w2t + (long)blockIdx.y * BN * FFDIM + (long)sk * KSPLIT;
    f32x4 acc[4][4] = {};
    gemm_core<BM, BN, BK, WM, WN>(A, FFDIM, B, FFDIM, KSPLIT, acc, lA, lB);

    float* out = part + (long)sk * (NB * SEQ) * DMODEL;
    const int lane = threadIdx.x & 63, wave = threadIdx.x >> 6;
    const int wr = wave >> 1, wc = wave & 1, l15 = lane & 15, l4 = lane >> 4;
#pragma unroll
    for (int fm = 0; fm < 4; ++fm)
#pragma unroll
        for (int fn = 0; fn < 4; ++fn)
#pragma unroll
            for (int r = 0; r < 4; ++r) {
                const int row = blockIdx.x * BM + wr * WM + fm * 16 + l4 * 4 + r;
                const int col = blockIdx.y * BN + wc * WN + fn * 16 + l15;
                out[(long)row * DMODEL + col] = acc[fm][fn][r];
            }
}

// ---------------------------------------------------------------------------
// Fused: h += sum_k part[k] + b2 (residual), then optionally y = LN(h) with
// next layer's ln1 params. One block per row (2048 blocks).
// ---------------------------------------------------------------------------
__global__ __launch_bounds__(256) void k_red2ln(const float* __restrict__ part,
                                                const float* __restrict__ b2,
                                                float* __restrict__ h,
                                                const float* __restrict__ lnw,
                                                const float* __restrict__ lnb,
                                                bf16* __restrict__ y,
                                                int do_ln)
{
    constexpr long NELT = (long)NB * SEQ * DMODEL / 4;   // float4 count
    const long row = blockIdx.x;
    const int tid = threadIdx.x;
    const long i = row * (DMODEL / 4) + tid;
    float4 s = ((const float4*)part)[i];
    const float4 s1 = ((const float4*)part)[i + NELT];
    const float4 s2 = ((const float4*)part)[i + 2 * NELT];
    const float4 s3 = ((const float4*)part)[i + 3 * NELT];
    const float4 bv = ((const float4*)b2)[tid];
    float4 hv = ((float4*)h)[i];
    hv.x += s.x + s1.x + s2.x + s3.x + bv.x;
    hv.y += s.y + s1.y + s2.y + s3.y + bv.y;
    hv.z += s.z + s1.z + s2.z + s3.z + bv.z;
    hv.w += s.w + s1.w + s2.w + s3.w + bv.w;
    ((float4*)h)[i] = hv;

    if (!do_ln) return;
    float ss  = hv.x + hv.y + hv.z + hv.w;
    float ss2 = hv.x * hv.x + hv.y * hv.y + hv.z * hv.z + hv.w * hv.w;
#pragma unroll
    for (int off = 32; off; off >>= 1) { ss += __shfl_xor(ss, off); ss2 += __shfl_xor(ss2, off); }
    __shared__ float rs[4], rs2[4];
    const int wave = tid >> 6;
    if ((tid & 63) == 0) { rs[wave] = ss; rs2[wave] = ss2; }
    __syncthreads();
    const float S1 = rs[0] + rs[1] + rs[2] + rs[3];
    const float S2 = rs2[0] + rs2[1] + rs2[2] + rs2[3];
    const float mean = S1 * (1.0f / DMODEL);
    const float var  = S2 * (1.0f / DMODEL) - mean * mean;
    const float rstd = rsqrtf(var + 1e-5f);
    const float4 wv = ((const float4*)lnw)[tid];
    const float4 lb = ((const float4*)lnb)[tid];
    uint2 o;
    o.x = (u32)f2bu((hv.x - mean) * rstd * wv.x + lb.x) |
          ((u32)f2bu((hv.y - mean) * rstd * wv.y + lb.y) << 16);
    o.y = (u32)f2bu((hv.z - mean) * rstd * wv.z + lb.z) |
          ((u32)f2bu((hv.w - mean) * rstd * wv.w + lb.w) << 16);
    ((uint2*)(y + row * DMODEL))[tid] = o;
}

// ---------------------------------------------------------------------------
extern "C" void kernel_launch(void* const* d_in, const int* in_sizes, int n_in,
                              void* d_out, int out_size, void* d_ws, size_t ws_size,
                              hipStream_t stream)
{
    const float* x    = (const float*)d_in[0];
    const float* ln1w = (const float*)d_in[1];
    const float* ln1b = (const float*)d_in[2];
    const float* qw   = (const float*)d_in[3];
    const float* qb   = (const float*)d_in[4];
    const float* kw   = (const float*)d_in[5];
    const float* kb   = (const float*)d_in[6];
    const float* vw   = (const float*)d_in[7];
    const float* vb   = (const float*)d_in[8];
    const float* ln2w = (const float*)d_in[9];
    const float* ln2b = (const float*)d_in[10];
    const float* w1   = (const float*)d_in[11];
    const float* b1   = (const float*)d_in[12];
    const float* w2   = (const float*)d_in[13];
    const float* b2   = (const float*)d_in[14];

    char* ws = (char*)d_ws;
    const size_t MB = 1024 * 1024;
    bf16* y    = (bf16*)(ws + 0 * MB);    // [2048,1024] bf16 : 4MB
    bf16* zb   = (bf16*)(ws + 4 * MB);    // [2048,1024] bf16 : 4MB
    bf16* qh   = (bf16*)(ws + 8 * MB);    // [B*H,512,64]     : 4MB
    bf16* kh   = (bf16*)(ws + 12 * MB);   // [B*H,512,64]     : 4MB
    bf16* vt   = (bf16*)(ws + 16 * MB);   // [B*H,64,512]     : 4MB
    bf16* ff1  = (bf16*)(ws + 20 * MB);   // [2048,4096]      : 16MB
    bf16* w1t  = (bf16*)(ws + 36 * MB);   // [4096,1024]      : 8MB
    bf16* w2t  = (bf16*)(ws + 44 * MB);   // [1024,4096]      : 8MB
    float* part = (float*)(ws + 53 * MB); // [4,2048,1024] f32: 32MB

    float* h = (float*)d_out;
    hipMemcpyAsync(d_out, x, (size_t)NB * SEQ * DMODEL * sizeof(float),
                   hipMemcpyDeviceToDevice, stream);

    // initial LN1 for layer 0
    k_ln<<<NB * SEQ, 256, 0, stream>>>(h, ln1w, ln1b, y);

    for (int l = 0; l < NLAYER; ++l) {
        k_qkv2<<<dim3(4, NB * NHEAD), 256, 0, stream>>>(
            y, qw + (long)l * 65536, kw + (long)l * 65536, vw + (long)l * 65536,
            qb + l * NHEAD * HDIM, kb + l * NHEAD * HDIM, vb + l * NHEAD * HDIM,
            qh, kh, vt);
        k_flash<<<dim3(SEQ / 64, NB * NHEAD), 256, 0, stream>>>(qh, kh, vt, h);
        k_ln<<<NB * SEQ, 256, 0, stream>>>(h, ln2w + l * DMODEL, ln2b + l * DMODEL, zb);
        k_transw<<<2048, 256, 0, stream>>>(w1 + (long)l * DMODEL * FFDIM,
                                           w2 + (long)l * DMODEL * FFDIM, w1t, w2t);
        k_gemm1<<<dim3(16, 32), 256, 0, stream>>>(zb, w1t, b1 + l * FFDIM, ff1);
        k_gemm2<<<dim3(16, 8, 4), 256, 0, stream>>>(ff1, w2t, part);
        const int last = (l == NLAYER - 1);
        k_red2ln<<<NB * SEQ, 256, 0, stream>>>(part, b2 + l * DMODEL, h,
                                               ln1w + (l + 1) * DMODEL * (1 - last),
                                               ln1b + (l + 1) * DMODEL * (1 - last),
                                               y, !last);
    }
}

// Round 6
// 955.205 us; speedup vs baseline: 1.1799x; 1.0557x over previous
//
#include <hip/hip_runtime.h>
#include <hip/hip_bf16.h>

typedef __hip_bfloat16 bf16;
typedef __bf16 bf16x8 __attribute__((ext_vector_type(8)));
typedef float f32x4 __attribute__((ext_vector_type(4)));
typedef unsigned short u16;
typedef unsigned int u32;

#define SEQ 512
#define DMODEL 1024
#define FFDIM 4096
#define NHEAD 16
#define HDIM 64
#define NB 4
#define NLAYER 8

#define SBAR() asm volatile("s_barrier" ::: "memory")

__device__ __forceinline__ u16 f2bu(float f) {
    union { bf16 h; u16 u; } c; c.h = __float2bfloat16(f); return c.u;
}

// async global->LDS, 16B per lane. LDS dest must be linear in lane order.
__device__ __forceinline__ void gload16(const bf16* g, bf16* l) {
    __builtin_amdgcn_global_load_lds(
        (const __attribute__((address_space(1))) unsigned int*)g,
        (__attribute__((address_space(3))) unsigned int*)l,
        16, 0, 0);
}

// ---------------------------------------------------------------------------
// Deep-pipelined NT GEMM core: 256(M) x 128(N) tile, BK=64, 512 threads
// (8 waves, 2Mx4N). Double-buffered LDS, counted vmcnt(6) (loads stay 2
// K-tiles in flight across raw s_barriers), st_16x32 swizzle via
// inverse-swizzled global source + swizzled ds_read (gload_lds dest linear).
// C[m,n] = sum_k A[m,k]*B[n,k]. acc[8][2] per wave (wave tile 128x32).
// ---------------------------------------------------------------------------
__device__ __forceinline__ void gemm_pipe(
    const bf16* __restrict__ A, int lda,
    const bf16* __restrict__ B, int ldb,
    int nkt,                    // number of K-tiles (K = nkt*64)
    f32x4 (&acc)[8][2],
    char* lA, char* lB)         // lA: 2 x 32KB, lB: 2 x 16KB
{
    const int tid = threadIdx.x;
    const int lane = tid & 63;
    const int wave = tid >> 6;
    const int wr = wave >> 2, wc = wave & 3;
    const int l15 = lane & 15, l4 = lane >> 4;

    // stage one K-tile (A 256x64, B 128x64) into buffer c, pre-swizzled source
    auto stage = [&](int c, int t) {
        const bf16* Ak = A + t * 64;
        const bf16* Bk = B + t * 64;
        bf16* dA = (bf16*)(lA + c * 32768);
        bf16* dB = (bf16*)(lB + c * 16384);
#pragma unroll
        for (int it = 0; it < 4; ++it) {
            const int e = (it * 512 + tid) * 8;
            const int r = e >> 6;
            const int cb = (e & 63) * 2;
            const int sc = (cb ^ (((r >> 2) & 1) << 5)) >> 1;
            gload16(Ak + (long)r * lda + sc, dA + e);
        }
#pragma unroll
        for (int it = 0; it < 2; ++it) {
            const int e = (it * 512 + tid) * 8;
            const int r = e >> 6;
            const int cb = (e & 63) * 2;
            const int sc = (cb ^ (((r >> 2) & 1) << 5)) >> 1;
            gload16(Bk + (long)r * ldb + sc, dB + e);
        }
    };
    // loads per tile per thread = 6 (A:4 + B:2)

    stage(0, 0);
    stage(1, 1);
    asm volatile("s_waitcnt vmcnt(6)" ::: "memory");   // tile 0 resident
    SBAR();

    for (int t = 0; t < nkt; ++t) {
        const int cur = t & 1;
        const char* bA = lA + cur * 32768;
        const char* bB = lB + cur * 16384;

        // B fragments: fn x ks (shared across all quadrants)
        bf16x8 bf_[2][2];
#pragma unroll
        for (int fn = 0; fn < 2; ++fn)
#pragma unroll
            for (int ks = 0; ks < 2; ++ks) {
                const int row = wc * 32 + fn * 16 + l15;
                int byte = row * 128 + (ks * 32 + l4 * 8) * 2;
                byte ^= ((row >> 2) & 1) << 5;
                bf_[fn][ks] = *(const bf16x8*)(bB + byte);
            }
        // 4 quadrants of 2 fm rows each
#pragma unroll
        for (int q = 0; q < 4; ++q) {
            bf16x8 af[2][2];
#pragma unroll
            for (int i = 0; i < 2; ++i)
#pragma unroll
                for (int ks = 0; ks < 2; ++ks) {
                    const int row = wr * 128 + (q * 2 + i) * 16 + l15;
                    int byte = row * 128 + (ks * 32 + l4 * 8) * 2;
                    byte ^= ((row >> 2) & 1) << 5;
                    af[i][ks] = *(const bf16x8*)(bA + byte);
                }
            __builtin_amdgcn_s_setprio(1);
#pragma unroll
            for (int i = 0; i < 2; ++i)
#pragma unroll
                for (int fn = 0; fn < 2; ++fn)
#pragma unroll
                    for (int ks = 0; ks < 2; ++ks)
                        acc[q * 2 + i][fn] = __builtin_amdgcn_mfma_f32_16x16x32_bf16(
                            af[i][ks], bf_[fn][ks], acc[q * 2 + i][fn], 0, 0, 0);
            __builtin_amdgcn_s_setprio(0);
        }
        SBAR();                     // all waves done reading buf[cur]
        if (t + 2 < nkt) {
            stage(cur, t + 2);      // overwrite dead buffer, stays in flight
            asm volatile("s_waitcnt vmcnt(6)" ::: "memory");  // tile t+1 landed
        } else {
            asm volatile("s_waitcnt vmcnt(0)" ::: "memory");
        }
        SBAR();                     // staged/landed tile visible to all waves
    }
}

// ---------------------------------------------------------------------------
// LayerNorm: h (fp32, row of 1024) -> out bf16
// ---------------------------------------------------------------------------
__global__ __launch_bounds__(256) void k_ln(const float* __restrict__ h,
                                            const float* __restrict__ w,
                                            const float* __restrict__ bp,
                                            bf16* __restrict__ out)
{
    const int row = blockIdx.x;
    const int tid = threadIdx.x;
    const float4 x = ((const float4*)(h + (long)row * DMODEL))[tid];
    float s  = x.x + x.y + x.z + x.w;
    float s2 = x.x * x.x + x.y * x.y + x.z * x.z + x.w * x.w;
#pragma unroll
    for (int off = 32; off; off >>= 1) { s += __shfl_xor(s, off); s2 += __shfl_xor(s2, off); }
    __shared__ float rs[4], rs2[4];
    const int wave = tid >> 6;
    if ((tid & 63) == 0) { rs[wave] = s; rs2[wave] = s2; }
    __syncthreads();
    const float S1 = rs[0] + rs[1] + rs[2] + rs[3];
    const float S2 = rs2[0] + rs2[1] + rs2[2] + rs2[3];
    const float mean = S1 * (1.0f / DMODEL);
    const float var  = S2 * (1.0f / DMODEL) - mean * mean;
    const float rstd = rsqrtf(var + 1e-5f);
    const float4 wv = ((const float4*)w)[tid];
    const float4 bv = ((const float4*)bp)[tid];
    uint2 o;
    o.x = (u32)f2bu((x.x - mean) * rstd * wv.x + bv.x) |
          ((u32)f2bu((x.y - mean) * rstd * wv.y + bv.y) << 16);
    o.y = (u32)f2bu((x.z - mean) * rstd * wv.z + bv.z) |
          ((u32)f2bu((x.w - mean) * rstd * wv.w + bv.w) << 16);
    ((uint2*)(out + (long)row * DMODEL))[tid] = o;
}

// ---------------------------------------------------------------------------
// Combined weight transpose for one layer (vectorized): w1 -> w1t, w2 -> w2t,
// fp32 -> bf16. grid 2048 blocks.
// ---------------------------------------------------------------------------
__global__ __launch_bounds__(256) void k_transw(const float* __restrict__ w1,
                                                const float* __restrict__ w2,
                                                bf16* __restrict__ w1t,
                                                bf16* __restrict__ w2t)
{
    __shared__ float t[64][65];
    int bid = blockIdx.x;
    const float* src; bf16* dst; int R, C, rb, cb;
    if (bid < 1024) {
        src = w1; dst = w1t; R = DMODEL; C = FFDIM;
        rb = (bid >> 6) << 6; cb = (bid & 63) << 6;
    } else {
        bid -= 1024;
        src = w2; dst = w2t; R = FFDIM; C = DMODEL;
        rb = (bid >> 4) << 6; cb = (bid & 15) << 6;
    }
    const int tid = threadIdx.x;
    const int lr = tid >> 4;           // 0..15
    const int lc = (tid & 15) * 4;     // 0,4,...,60
#pragma unroll
    for (int i = 0; i < 4; ++i) {
        const int r = i * 16 + lr;
        const float4 v = *(const float4*)(src + (long)(rb + r) * C + cb + lc);
        t[r][lc] = v.x; t[r][lc + 1] = v.y; t[r][lc + 2] = v.z; t[r][lc + 3] = v.w;
    }
    __syncthreads();
#pragma unroll
    for (int i = 0; i < 4; ++i) {
        const int c = i * 16 + lr;      // output row (= src col)
        uint2 o;
        o.x = (u32)f2bu(t[lc][c])     | ((u32)f2bu(t[lc + 1][c]) << 16);
        o.y = (u32)f2bu(t[lc + 2][c]) | ((u32)f2bu(t[lc + 3][c]) << 16);
        *(uint2*)(dst + (long)(cb + c) * R + rb + lc) = o;
    }
}

// ---------------------------------------------------------------------------
// Merged QKV with in-flight fp32->bf16 weight conversion. grid (4, B*H).
// q scaled 1/8; v stored transposed vt[e][s].
// ---------------------------------------------------------------------------
__global__ __launch_bounds__(256) void k_qkv2(const bf16* __restrict__ y,
                                              const float* __restrict__ qwl,
                                              const float* __restrict__ kwl,
                                              const float* __restrict__ vwl,
                                              const float* __restrict__ qb,
                                              const float* __restrict__ kb,
                                              const float* __restrict__ vb,
                                              bf16* __restrict__ qh,
                                              bf16* __restrict__ kh,
                                              bf16* __restrict__ vt)
{
    __shared__ __align__(16) char lmem[128 * 64 * 2 + 64 * 64 * 2];  // lA 16KB + lB 8KB
    bf16* lA = (bf16*)lmem;
    char* lBb = lmem + 128 * 64 * 2;

    const int tid = threadIdx.x;
    const int lane = tid & 63, wave = tid >> 6;
    const int l15 = lane & 15, l4 = lane >> 4;
    const int z = blockIdx.y;             // b*H + hd
    const int b = z >> 4, hd = z & 15;
    const bf16* A = y + (long)b * SEQ * DMODEL + hd * HDIM + (long)blockIdx.x * 128 * DMODEL;

    // stage A tile [128][64] linear
#pragma unroll
    for (int it = 0; it < 4; ++it) {
        const int f = (it * 256 + tid) * 8;
        const int r = f >> 6, c = f & 63;
        gload16(A + (long)r * DMODEL + c, lA + f);
    }
    __syncthreads();

    // A-fragments to registers: rows wave*32 + fm*16 + l15
    bf16x8 qa[2][2];
#pragma unroll
    for (int fm = 0; fm < 2; ++fm)
#pragma unroll
        for (int ks = 0; ks < 2; ++ks)
            qa[fm][ks] = *(const bf16x8*)(lA + (wave * 32 + fm * 16 + l15) * 64 + ks * 32 + l4 * 8);

    for (int t = 0; t < 3; ++t) {
        __syncthreads();   // lB reuse safe
        // stage B [64][64] from fp32 weights, convert + XOR swizzle
        const float* Bsrc = ((t == 0) ? qwl : (t == 1) ? kwl : vwl) + (long)hd * HDIM * HDIM;
#pragma unroll
        for (int it = 0; it < 4; ++it) {
            const int f = (it * 256 + tid) * 4;         // float index
            const float4 v = *(const float4*)(Bsrc + f);
            uint2 o;
            o.x = (u32)f2bu(v.x) | ((u32)f2bu(v.y) << 16);
            o.y = (u32)f2bu(v.z) | ((u32)f2bu(v.w) << 16);
            const int row = f >> 6;
            const int byte = (f << 1) ^ ((row & 7) << 4);
            *(uint2*)(lBb + byte) = o;
        }
        __syncthreads();

        bf16x8 bfr[4][2];
#pragma unroll
        for (int fn = 0; fn < 4; ++fn)
#pragma unroll
            for (int ks = 0; ks < 2; ++ks) {
                const int row = fn * 16 + l15;
                int byte = (row << 7) + ((ks * 32 + l4 * 8) << 1);
                byte ^= (row & 7) << 4;
                bfr[fn][ks] = *(const bf16x8*)(lBb + byte);
            }
        f32x4 acc[2][4] = {};
#pragma unroll
        for (int ks = 0; ks < 2; ++ks)
#pragma unroll
            for (int fm = 0; fm < 2; ++fm)
#pragma unroll
                for (int fn = 0; fn < 4; ++fn)
                    acc[fm][fn] = __builtin_amdgcn_mfma_f32_16x16x32_bf16(
                        qa[fm][ks], bfr[fn][ks], acc[fm][fn], 0, 0, 0);

        const float* bias = (t == 0) ? qb : (t == 1) ? kb : vb;
#pragma unroll
        for (int fm = 0; fm < 2; ++fm)
#pragma unroll
            for (int fn = 0; fn < 4; ++fn)
#pragma unroll
                for (int r = 0; r < 4; ++r) {
                    const int srow = blockIdx.x * 128 + wave * 32 + fm * 16 + l4 * 4 + r;
                    const int e = fn * 16 + l15;
                    float v = acc[fm][fn][r] + bias[hd * HDIM + e];
                    if (t == 0) {
                        qh[((long)z * SEQ + srow) * HDIM + e] = __float2bfloat16(v * 0.125f);
                    } else if (t == 1) {
                        kh[((long)z * SEQ + srow) * HDIM + e] = __float2bfloat16(v);
                    } else {
                        vt[((long)z * HDIM + e) * SEQ + srow] = __float2bfloat16(v);
                    }
                }
    }
}

// ---------------------------------------------------------------------------
// Flash attention: per block one (b,hd) head and 64 q-rows; loop over 8
// kv-tiles of 64 keys. grid (SEQ/64=8, B*H). h += O/l (residual).
// ---------------------------------------------------------------------------
__global__ __launch_bounds__(256) void k_flash(const bf16* __restrict__ qh,
                                               const bf16* __restrict__ kh,
                                               const bf16* __restrict__ vt,
                                               float* __restrict__ h)
{
    __shared__ __align__(16) char lmem[24576];
    bf16* lQ = (bf16*)lmem;
    char* lKb = lmem + 8192;
    char* lVb = lmem + 16384;

    const int tid = threadIdx.x;
    const int lane = tid & 63, wave = tid >> 6;
    const int l15 = lane & 15, l4 = lane >> 4;
    const int z = blockIdx.y;
    const int b = z >> 4, hd = z & 15;
    const int q0 = blockIdx.x * 64;

    const bf16* Qsrc = qh + ((long)z * SEQ + q0) * HDIM;
#pragma unroll
    for (int it = 0; it < 2; ++it) {
        const int f = (it * 256 + tid) * 8;
        gload16(Qsrc + f, lQ + f);
    }
    __syncthreads();

    bf16x8 qa[2];
#pragma unroll
    for (int ks = 0; ks < 2; ++ks)
        qa[ks] = *(const bf16x8*)(lQ + (wave * 16 + l15) * 64 + ks * 32 + l4 * 8);

    char* lPb = lmem + wave * 2048;   // wave-private, aliases its own lQ rows

    f32x4 O[4] = {};
    float mrun[4], lrun[4];
#pragma unroll
    for (int r = 0; r < 4; ++r) { mrun[r] = -1e30f; lrun[r] = 0.0f; }

    for (int kv = 0; kv < SEQ / 64; ++kv) {
        __syncthreads();
        const bf16* Ksrc = kh + ((long)z * SEQ + kv * 64) * HDIM;
#pragma unroll
        for (int it = 0; it < 2; ++it) {
            const int f = (it * 256 + tid) * 8;
            const int r = f >> 6;
            const uint4 v = *(const uint4*)(Ksrc + f);
            *(uint4*)(lKb + ((f << 1) ^ ((r & 7) << 4))) = v;
        }
        const bf16* Vsrc = vt + (long)z * HDIM * SEQ + kv * 64;
#pragma unroll
        for (int it = 0; it < 2; ++it) {
            const int f = (it * 256 + tid) * 8;
            const int r = f >> 6, c = f & 63;
            const uint4 v = *(const uint4*)(Vsrc + (long)r * SEQ + c);
            *(uint4*)(lVb + ((f << 1) ^ ((r & 7) << 4))) = v;
        }
        __syncthreads();

        f32x4 sa[4];
#pragma unroll
        for (int fn = 0; fn < 4; ++fn) sa[fn] = (f32x4){0.f, 0.f, 0.f, 0.f};
#pragma unroll
        for (int ks = 0; ks < 2; ++ks)
#pragma unroll
            for (int fn = 0; fn < 4; ++fn) {
                const int row = fn * 16 + l15;
                int byte = (row << 7) + ((ks * 32 + l4 * 8) << 1);
                byte ^= (row & 7) << 4;
                const bf16x8 kb_ = *(const bf16x8*)(lKb + byte);
                sa[fn] = __builtin_amdgcn_mfma_f32_16x16x32_bf16(qa[ks], kb_, sa[fn], 0, 0, 0);
            }

#pragma unroll
        for (int r = 0; r < 4; ++r) {
            float mx = fmaxf(fmaxf(sa[0][r], sa[1][r]), fmaxf(sa[2][r], sa[3][r]));
#pragma unroll
            for (int m_ = 1; m_ < 16; m_ <<= 1) mx = fmaxf(mx, __shfl_xor(mx, m_));
            const float nm = fmaxf(mrun[r], mx);
            const float al = __expf(mrun[r] - nm);
            mrun[r] = nm;
            float p0 = __expf(sa[0][r] - nm), p1 = __expf(sa[1][r] - nm);
            float p2 = __expf(sa[2][r] - nm), p3 = __expf(sa[3][r] - nm);
            float ps = p0 + p1 + p2 + p3;
#pragma unroll
            for (int m_ = 1; m_ < 16; m_ <<= 1) ps += __shfl_xor(ps, m_);
            lrun[r] = lrun[r] * al + ps;
#pragma unroll
            for (int fn = 0; fn < 4; ++fn) O[fn][r] *= al;
            const int row = l4 * 4 + r;
            const int rsw = (row & 7) << 4;
            const int rb = row << 7;
            *(u16*)(lPb + ((rb + ((0 * 16 + l15) << 1)) ^ rsw)) = f2bu(p0);
            *(u16*)(lPb + ((rb + ((1 * 16 + l15) << 1)) ^ rsw)) = f2bu(p1);
            *(u16*)(lPb + ((rb + ((2 * 16 + l15) << 1)) ^ rsw)) = f2bu(p2);
            *(u16*)(lPb + ((rb + ((3 * 16 + l15) << 1)) ^ rsw)) = f2bu(p3);
        }

#pragma unroll
        for (int ks = 0; ks < 2; ++ks) {
            const int rowp = l15;
            int pbyte = (rowp << 7) + ((ks * 32 + l4 * 8) << 1);
            pbyte ^= (rowp & 7) << 4;
            const bf16x8 pa = *(const bf16x8*)(lPb + pbyte);
#pragma unroll
            for (int fn = 0; fn < 4; ++fn) {
                const int row = fn * 16 + l15;
                int byte = (row << 7) + ((ks * 32 + l4 * 8) << 1);
                byte ^= (row & 7) << 4;
                const bf16x8 vb_ = *(const bf16x8*)(lVb + byte);
                O[fn] = __builtin_amdgcn_mfma_f32_16x16x32_bf16(pa, vb_, O[fn], 0, 0, 0);
            }
        }
    }

    float rinv[4];
#pragma unroll
    for (int r = 0; r < 4; ++r) rinv[r] = 1.0f / lrun[r];
#pragma unroll
    for (int fn = 0; fn < 4; ++fn)
#pragma unroll
        for (int r = 0; r < 4; ++r) {
            const int srow = q0 + wave * 16 + l4 * 4 + r;
            const int e = fn * 16 + l15;
            h[((long)b * SEQ + srow) * DMODEL + hd * HDIM + e] += O[fn][r] * rinv[r];
        }
}

// ---------------------------------------------------------------------------
// MLP GEMM1 (pipelined): ff1 = gelu(z @ w1t^T + b1). grid (8, 32), 512 thr.
// ---------------------------------------------------------------------------
__global__ __launch_bounds__(512, 2) void k_gemm1(const bf16* __restrict__ zb,
                                                  const bf16* __restrict__ w1t,
                                                  const float* __restrict__ b1,
                                                  bf16* __restrict__ ff1)
{
    __shared__ __align__(16) char lmem[98304];   // lA 2x32KB + lB 2x16KB
    const bf16* A = zb + (long)blockIdx.x * 256 * DMODEL;
    const bf16* B = w1t + (long)blockIdx.y * 128 * DMODEL;
    f32x4 acc[8][2] = {};
    gemm_pipe(A, DMODEL, B, DMODEL, DMODEL / 64, acc, lmem, lmem + 65536);

    const int lane = threadIdx.x & 63, wave = threadIdx.x >> 6;
    const int wr = wave >> 2, wc = wave & 3;
    const int l15 = lane & 15, l4 = lane >> 4;
#pragma unroll
    for (int fm = 0; fm < 8; ++fm)
#pragma unroll
        for (int fn = 0; fn < 2; ++fn)
#pragma unroll
            for (int r = 0; r < 4; ++r) {
                const int row = blockIdx.x * 256 + wr * 128 + fm * 16 + l4 * 4 + r;
                const int col = blockIdx.y * 128 + wc * 32 + fn * 16 + l15;
                const float x = acc[fm][fn][r] + b1[col];
                const float g = 0.5f * x * (1.0f + erff(x * 0.70710678118f));
                ff1[(long)row * FFDIM + col] = __float2bfloat16(g);
            }
}

// ---------------------------------------------------------------------------
// MLP GEMM2 (pipelined, split-K=4): part[sk] = ff1[:,sk] @ w2t[:,sk]^T.
// grid (8, 8, 4), 512 threads.
// ---------------------------------------------------------------------------
__global__ __launch_bounds__(512, 2) void k_gemm2(const bf16* __restrict__ ff1,
                                                  const bf16* __restrict__ w2t,
                                                  float* __restrict__ part)
{
    __shared__ __align__(16) char lmem[98304];
    const int sk = blockIdx.z;
    const bf16* A = ff1 + (long)blockIdx.x * 256 * FFDIM + (long)sk * 1024;
    const bf16* B = w2t + (long)blockIdx.y * 128 * FFDIM + (long)sk * 1024;
    f32x4 acc[8][2] = {};
    gemm_pipe(A, FFDIM, B, FFDIM, 1024 / 64, acc, lmem, lmem + 65536);

    float* out = part + (long)sk * (NB * SEQ) * DMODEL;
    const int lane = threadIdx.x & 63, wave = threadIdx.x >> 6;
    const int wr = wave >> 2, wc = wave & 3;
    const int l15 = lane & 15, l4 = lane >> 4;
#pragma unroll
    for (int fm = 0; fm < 8; ++fm)
#pragma unroll
        for (int fn = 0; fn < 2; ++fn)
#pragma unroll
            for (int r = 0; r < 4; ++r) {
                const int row = blockIdx.x * 256 + wr * 128 + fm * 16 + l4 * 4 + r;
                const int col = blockIdx.y * 128 + wc * 32 + fn * 16 + l15;
                out[(long)row * DMODEL + col] = acc[fm][fn][r];
            }
}

// ---------------------------------------------------------------------------
// Fused: h += sum_k part[k] + b2 (residual), then optionally y = LN(h) with
// next layer's ln1 params. One block per row (2048 blocks).
// ---------------------------------------------------------------------------
__global__ __launch_bounds__(256) void k_red2ln(const float* __restrict__ part,
                                                const float* __restrict__ b2,
                                                float* __restrict__ h,
                                                const float* __restrict__ lnw,
                                                const float* __restrict__ lnb,
                                                bf16* __restrict__ y,
                                                int do_ln)
{
    constexpr long NELT = (long)NB * SEQ * DMODEL / 4;   // float4 count
    const long row = blockIdx.x;
    const int tid = threadIdx.x;
    const long i = row * (DMODEL / 4) + tid;
    float4 s = ((const float4*)part)[i];
    const float4 s1 = ((const float4*)part)[i + NELT];
    const float4 s2 = ((const float4*)part)[i + 2 * NELT];
    const float4 s3 = ((const float4*)part)[i + 3 * NELT];
    const float4 bv = ((const float4*)b2)[tid];
    float4 hv = ((float4*)h)[i];
    hv.x += s.x + s1.x + s2.x + s3.x + bv.x;
    hv.y += s.y + s1.y + s2.y + s3.y + bv.y;
    hv.z += s.z + s1.z + s2.z + s3.z + bv.z;
    hv.w += s.w + s1.w + s2.w + s3.w + bv.w;
    ((float4*)h)[i] = hv;

    if (!do_ln) return;
    float ss  = hv.x + hv.y + hv.z + hv.w;
    float ss2 = hv.x * hv.x + hv.y * hv.y + hv.z * hv.z + hv.w * hv.w;
#pragma unroll
    for (int off = 32; off; off >>= 1) { ss += __shfl_xor(ss, off); ss2 += __shfl_xor(ss2, off); }
    __shared__ float rs[4], rs2[4];
    const int wave = tid >> 6;
    if ((tid & 63) == 0) { rs[wave] = ss; rs2[wave] = ss2; }
    __syncthreads();
    const float S1 = rs[0] + rs[1] + rs[2] + rs[3];
    const float S2 = rs2[0] + rs2[1] + rs2[2] + rs2[3];
    const float mean = S1 * (1.0f / DMODEL);
    const float var  = S2 * (1.0f / DMODEL) - mean * mean;
    const float rstd = rsqrtf(var + 1e-5f);
    const float4 wv = ((const float4*)lnw)[tid];
    const float4 lb = ((const float4*)lnb)[tid];
    uint2 o;
    o.x = (u32)f2bu((hv.x - mean) * rstd * wv.x + lb.x) |
          ((u32)f2bu((hv.y - mean) * rstd * wv.y + lb.y) << 16);
    o.y = (u32)f2bu((hv.z - mean) * rstd * wv.z + lb.z) |
          ((u32)f2bu((hv.w - mean) * rstd * wv.w + lb.w) << 16);
    ((uint2*)(y + row * DMODEL))[tid] = o;
}

// ---------------------------------------------------------------------------
extern "C" void kernel_launch(void* const* d_in, const int* in_sizes, int n_in,
                              void* d_out, int out_size, void* d_ws, size_t ws_size,
                              hipStream_t stream)
{
    const float* x    = (const float*)d_in[0];
    const float* ln1w = (const float*)d_in[1];
    const float* ln1b = (const float*)d_in[2];
    const float* qw   = (const float*)d_in[3];
    const float* qb   = (const float*)d_in[4];
    const float* kw   = (const float*)d_in[5];
    const float* kb   = (const float*)d_in[6];
    const float* vw   = (const float*)d_in[7];
    const float* vb   = (const float*)d_in[8];
    const float* ln2w = (const float*)d_in[9];
    const float* ln2b = (const float*)d_in[10];
    const float* w1   = (const float*)d_in[11];
    const float* b1   = (const float*)d_in[12];
    const float* w2   = (const float*)d_in[13];
    const float* b2   = (const float*)d_in[14];

    char* ws = (char*)d_ws;
    const size_t MB = 1024 * 1024;
    bf16* y    = (bf16*)(ws + 0 * MB);    // [2048,1024] bf16 : 4MB
    bf16* zb   = (bf16*)(ws + 4 * MB);    // [2048,1024] bf16 : 4MB
    bf16* qh   = (bf16*)(ws + 8 * MB);    // [B*H,512,64]     : 4MB
    bf16* kh   = (bf16*)(ws + 12 * MB);   // [B*H,512,64]     : 4MB
    bf16* vt   = (bf16*)(ws + 16 * MB);   // [B*H,64,512]     : 4MB
    bf16* ff1  = (bf16*)(ws + 20 * MB);   // [2048,4096]      : 16MB
    bf16* w1t  = (bf16*)(ws + 36 * MB);   // [4096,1024]      : 8MB
    bf16* w2t  = (bf16*)(ws + 44 * MB);   // [1024,4096]      : 8MB
    float* part = (float*)(ws + 53 * MB); // [4,2048,1024] f32: 32MB

    float* h = (float*)d_out;
    hipMemcpyAsync(d_out, x, (size_t)NB * SEQ * DMODEL * sizeof(float),
                   hipMemcpyDeviceToDevice, stream);

    // initial LN1 for layer 0
    k_ln<<<NB * SEQ, 256, 0, stream>>>(h, ln1w, ln1b, y);

    for (int l = 0; l < NLAYER; ++l) {
        k_qkv2<<<dim3(4, NB * NHEAD), 256, 0, stream>>>(
            y, qw + (long)l * 65536, kw + (long)l * 65536, vw + (long)l * 65536,
            qb + l * NHEAD * HDIM, kb + l * NHEAD * HDIM, vb + l * NHEAD * HDIM,
            qh, kh, vt);
        k_flash<<<dim3(SEQ / 64, NB * NHEAD), 256, 0, stream>>>(qh, kh, vt, h);
        k_ln<<<NB * SEQ, 256, 0, stream>>>(h, ln2w + l * DMODEL, ln2b + l * DMODEL, zb);
        k_transw<<<2048, 256, 0, stream>>>(w1 + (long)l * DMODEL * FFDIM,
                                           w2 + (long)l * DMODEL * FFDIM, w1t, w2t);
        k_gemm1<<<dim3(8, 32), 512, 0, stream>>>(zb, w1t, b1 + l * FFDIM, ff1);
        k_gemm2<<<dim3(8, 8, 4), 512, 0, stream>>>(ff1, w2t, part);
        const int last = (l == NLAYER - 1);
        k_red2ln<<<NB * SEQ, 256, 0, stream>>>(part, b2 + l * DMODEL, h,
                                               ln1w + (l + 1) * DMODEL * (1 - last),
                                               ln1b + (l + 1) * DMODEL * (1 - last),
                                               y, !last);
    }
}